// Round 6
// baseline (199.366 us; speedup 1.0000x reference)
//
#include <hip/hip_runtime.h>
#include <hip/hip_bf16.h>

#define NN   50000
#define NE   800000
#define F_IN 128
#define F_H  128
#define F_O  64

#define BINSHIFT 7                       // 128 nodes per bin
#define NBINS    ((NN + 127) >> 7)       // 391
#define CAP      2816                    // mean 2048, sd ~45 -> +17 sigma
#define EPB      2048                    // edges per binning block
#define RPSTRIDE 132                     // rp entries per bin (128+1, padded)

static constexpr int NB_G1  = (NN + 63) / 64;          // 782 GEMM1 blocks
static constexpr int NB_BIN = (NE + EPB - 1) / EPB;    // 391 binning blocks

typedef __bf16 bf16_8 __attribute__((ext_vector_type(8)));
typedef float  f32x4  __attribute__((ext_vector_type(4)));

// ---------------------------------------------------------------------------
// MFMA GEMM body (unscaled):  Y_bf16[r][c] = sum_k A[r][k]*W[k][c]
// Block = 64 rows (4 waves x 16 rows). W staged into LDS pre-swizzled to
// B-fragment layout [ks][c][n][q][j]; A-fragments straight from global.
// ---------------------------------------------------------------------------
template <typename AT, int K, int NOUT>
__device__ __forceinline__ void gemm_body(const AT* __restrict__ X,
                                          const float* __restrict__ W,
                                          __hip_bfloat16* __restrict__ Y,
                                          __hip_bfloat16* WB, int blk) {
    constexpr int NKS = K / 32;
    constexpr int NC  = NOUT / 16;
    const int t = threadIdx.x;
    for (int f = t; f < K * NOUT; f += 256) {
        int k = f / NOUT, n = f % NOUT;
        int ks = k >> 5, kr = k & 31, qq = kr >> 3, jj = kr & 7;
        int c = n >> 4, nn = n & 15;
        WB[(((ks * NC + c) * 16 + nn) * 4 + qq) * 8 + jj] = __float2bfloat16(W[f]);
    }
    __syncthreads();

    const int wave = t >> 6, lane = t & 63;
    const int r = lane & 15, q = lane >> 4;
    const int m0 = blk * 64 + wave * 16;
    int arow = m0 + r;
    if (arow >= NN) arow = NN - 1;  // clamp: garbage rows computed, never stored

    f32x4 acc[NC];
#pragma unroll
    for (int c = 0; c < NC; ++c) acc[c] = (f32x4){0.f, 0.f, 0.f, 0.f};

#pragma unroll
    for (int ks = 0; ks < NKS; ++ks) {
        bf16_8 a;
        if constexpr (sizeof(AT) == 4) {
            const float* xp = (const float*)X + (size_t)arow * K + ks * 32 + q * 8;
            float4 x0 = ((const float4*)xp)[0];
            float4 x1 = ((const float4*)xp)[1];
            a[0] = (__bf16)x0.x; a[1] = (__bf16)x0.y; a[2] = (__bf16)x0.z; a[3] = (__bf16)x0.w;
            a[4] = (__bf16)x1.x; a[5] = (__bf16)x1.y; a[6] = (__bf16)x1.z; a[7] = (__bf16)x1.w;
        } else {
            a = *(const bf16_8*)((const __hip_bfloat16*)X + (size_t)arow * K + ks * 32 + q * 8);
        }
#pragma unroll
        for (int c = 0; c < NC; ++c) {
            bf16_8 b = *(const bf16_8*)&WB[(((ks * NC + c) * 16 + r) * 4 + q) * 8];
            acc[c] = __builtin_amdgcn_mfma_f32_16x16x32_bf16(a, b, acc[c], 0, 0, 0);
        }
    }

#pragma unroll
    for (int c = 0; c < NC; ++c) {
#pragma unroll
        for (int i = 0; i < 4; ++i) {
            int gr = m0 + q * 4 + i;
            if (gr < NN)
                Y[(size_t)gr * NOUT + c * 16 + r] = __float2bfloat16(acc[c][i]);
        }
    }
}

// ---------------------------------------------------------------------------
// Fused: blocks [0, NB_BIN): bin edges by dst>>7 into packed binbuf AND count
//        per-node in-degrees (global atomics, overlapped with GEMM role);
//        blocks [NB_BIN, NB_BIN+NB_G1): GEMM1 (x@W1 -> Xw, raw/unscaled).
// Packed entry: (src << 7) | (dst & 127).  bincnt[b] ends as bin total.
// ---------------------------------------------------------------------------
__global__ __launch_bounds__(256) void k_fuseA(const float* __restrict__ X,
                                               const float* __restrict__ W1,
                                               __hip_bfloat16* __restrict__ Xw,
                                               const int* __restrict__ ei32,
                                               int* __restrict__ binbuf,
                                               unsigned* __restrict__ bincnt,
                                               unsigned* __restrict__ cnt) {
    __shared__ __align__(16) char smem[32768];  // GEMM WB (32KB) / binning hists
    const int t = threadIdx.x;

    if (blockIdx.x >= NB_BIN) {
        gemm_body<float, F_IN, F_H>(X, W1, Xw, (__hip_bfloat16*)smem,
                                    blockIdx.x - NB_BIN);
        return;
    }

    // ---- binning + degree-count role ----
    unsigned* hist = (unsigned*)smem;        // [NBINS]
    unsigned* base = hist + NBINS;           // [NBINS]
    unsigned* rank = base + NBINS;           // [NBINS]
    for (int i = t; i < NBINS; i += 256) { hist[i] = 0u; rank[i] = 0u; }
    __syncthreads();

    const bool is64 = ((ei32[1] | ei32[3] | ei32[5] | ei32[7]) == 0);
    const int e0 = blockIdx.x * EPB;
    int pk[8], bin[8], dd[8];
#pragma unroll
    for (int j = 0; j < 8; ++j) {
        int e = e0 + t + j * 256;
        if (e < NE) {
            int s, d;
            if (is64) {
                const long long* p = (const long long*)ei32;
                s = (int)p[e];
                d = (int)p[NE + e];
            } else {
                s = ei32[e];
                d = ei32[NE + e];
            }
            pk[j]  = (s << BINSHIFT) | (d & 127);
            bin[j] = d >> BINSHIFT;
            dd[j]  = d;
        } else bin[j] = -1;
    }
#pragma unroll
    for (int j = 0; j < 8; ++j) {
        if (bin[j] >= 0) {
            atomicAdd(&hist[bin[j]], 1u);
            atomicAdd(&cnt[dd[j]], 1u);      // global in-degree
        }
    }
    __syncthreads();
    for (int b = t; b < NBINS; b += 256)
        base[b] = atomicAdd(&bincnt[b], hist[b]);  // reserve contiguous chunk
    __syncthreads();
#pragma unroll
    for (int j = 0; j < 8; ++j) {
        if (bin[j] >= 0) {
            unsigned rk = atomicAdd(&rank[bin[j]], 1u);
            binbuf[(size_t)bin[j] * CAP + base[bin[j]] + rk] = pk[j];
        }
    }
}

// ---------------------------------------------------------------------------
// phaseC: one block (1024 threads) per bin of 128 dst nodes.
//  1. stage W2 swizzled into LDS; build bin-local CSR in LDS (hist, scan,
//     scatter) from binbuf; emit bin-local rp (u16) + srcs to global for agg2.
//  2. agg1 for the bin's nodes: gather Xw[s] * rsqrt(cnt[s]+1), self term,
//     relu(dinv_v*sum + b1) -> H1 tile in LDS ONLY (row stride 136 bf16 to
//     break the 16-row bank aliasing in the gemm A-reads).
//  3. GEMM2 on the LDS H1 tile -> Hw (prescaled by dinv_v) to global.
// ---------------------------------------------------------------------------
#define HS 136   // Htile row stride (bf16): 68 dwords -> rows 4 banks apart
__global__ __launch_bounds__(1024) void k_phaseC(const int* __restrict__ binbuf,
                                                 const unsigned* __restrict__ bincnt,
                                                 const unsigned* __restrict__ cnt,
                                                 const __hip_bfloat16* __restrict__ Xw,
                                                 const float* __restrict__ W2,
                                                 const float* __restrict__ b1,
                                                 __hip_bfloat16* __restrict__ Hw,
                                                 int* __restrict__ srcs_g,
                                                 unsigned short* __restrict__ rp_g) {
    __shared__ __align__(16) char smem[64000];
    __hip_bfloat16* Htile = (__hip_bfloat16*)smem;                    // 128*136*2 = 34816
    __hip_bfloat16* WB2   = (__hip_bfloat16*)(smem + 34816);          // 16384
    int*      srcsL = (int*)(smem + 34816 + 16384);                   // CAP*4 = 11264
    unsigned* h     = (unsigned*)(smem + 62464);                      // 512
    unsigned* cur   = (unsigned*)(smem + 62976);                      // 512
    float*    dv    = (float*)(smem + 63488);                         // 512

    const int b = blockIdx.x, t = threadIdx.x;

    // stage W2 (f32 -> bf16, B-fragment swizzle), zero hist
    for (int f = t; f < F_H * F_O; f += 1024) {
        int k = f / F_O, n = f % F_O;
        int ks = k >> 5, kr = k & 31, qq = kr >> 3, jj = kr & 7;
        int c = n >> 4, nn = n & 15;
        WB2[(((ks * 4 + c) * 16 + nn) * 4 + qq) * 8 + jj] = __float2bfloat16(W2[f]);
    }
    if (t < 128) h[t] = 0u;
    __syncthreads();

    const unsigned n = bincnt[b];
    const int* buf = binbuf + (size_t)b * CAP;
    for (unsigned i = t; i < n; i += 1024)
        atomicAdd(&h[buf[i] & 127], 1u);
    __syncthreads();
    if (t < 128) cur[t] = h[t];
    __syncthreads();
    for (int off = 1; off < 128; off <<= 1) {
        unsigned u = (t < 128 && t >= off) ? cur[t - off] : 0u;
        __syncthreads();
        if (t < 128) cur[t] += u;
        __syncthreads();
    }
    if (t < 128) {
        unsigned ex = cur[t] - h[t];                 // bin-local exclusive prefix
        rp_g[b * RPSTRIDE + t] = (unsigned short)ex;
        if (t == 0) rp_g[b * RPSTRIDE + 128] = (unsigned short)n;
        dv[t]  = rsqrtf((float)(h[t] + 1u));
        cur[t] = ex;                                 // scatter cursor
    }
    __syncthreads();
    for (unsigned i = t; i < n; i += 1024) {
        int p = buf[i];
        unsigned pos = atomicAdd(&cur[p & 127], 1u);
        int s = p >> BINSHIFT;
        srcsL[pos] = s;
        srcs_g[(size_t)b * CAP + pos] = s;           // for agg2
    }
    __syncthreads();
    // after scatter: cur[tl] = end index, cur[tl]-h[tl] = start index

    // ---- phase 2: aggregate 8 nodes per wave (16 waves) ----
    const int wave = t >> 6, lane = t & 63;
    const int fl = lane & 15, sub = lane >> 4;
    const float4 b1a = ((const float4*)b1)[fl * 2];
    const float4 b1b = ((const float4*)b1)[fl * 2 + 1];
    for (int nd = 0; nd < 8; ++nd) {
        const int tl    = wave * 8 + nd;
        const int gnode = (b << BINSHIFT) + tl;
        const unsigned i1 = cur[tl];
        const unsigned i0 = i1 - h[tl];
        float acc0[8], acc1[8];
        {   // self-loop term (weight dv on one sub-slot)
            int sv = (gnode < NN) ? gnode : 0;
            bf16_8 r = *(const bf16_8*)(Xw + (size_t)sv * F_H + fl * 8);
            float w = (sub == 0 && gnode < NN) ? dv[tl] : 0.f;
#pragma unroll
            for (int j = 0; j < 8; ++j) { acc0[j] = w * (float)r[j]; acc1[j] = 0.f; }
        }
        unsigned i = i0 + sub;
        for (; i + 4 < i1; i += 8) {
            int s0 = srcsL[i], s1 = srcsL[i + 4];
            float w0 = rsqrtf((float)(cnt[s0] + 1u));
            float w1 = rsqrtf((float)(cnt[s1] + 1u));
            bf16_8 r0 = *(const bf16_8*)(Xw + (size_t)s0 * F_H + fl * 8);
            bf16_8 r1 = *(const bf16_8*)(Xw + (size_t)s1 * F_H + fl * 8);
#pragma unroll
            for (int j = 0; j < 8; ++j) {
                acc0[j] += w0 * (float)r0[j];
                acc1[j] += w1 * (float)r1[j];
            }
        }
        if (i < i1) {
            int s = srcsL[i];
            float w = rsqrtf((float)(cnt[s] + 1u));
            bf16_8 r = *(const bf16_8*)(Xw + (size_t)s * F_H + fl * 8);
#pragma unroll
            for (int j = 0; j < 8; ++j) acc0[j] += w * (float)r[j];
        }
#pragma unroll
        for (int j = 0; j < 8; ++j) {
            float a = acc0[j] + acc1[j];
            a += __shfl_xor(a, 16, 64);
            a += __shfl_xor(a, 32, 64);
            acc0[j] = a;
        }
        if (sub == 0) {
            const float bias[8] = {b1a.x, b1a.y, b1a.z, b1a.w, b1b.x, b1b.y, b1b.z, b1b.w};
            bf16_8 o;
#pragma unroll
            for (int j = 0; j < 8; ++j)
                o[j] = (__bf16)fmaxf(dv[tl] * acc0[j] + bias[j], 0.f);
            *(bf16_8*)(Htile + tl * HS + fl * 8) = o;
        }
    }
    __syncthreads();

    // ---- phase 3: GEMM2 on LDS H1 tile. wave -> (row-tile, c-pair) ----
    {
        const int r = lane & 15, q = lane >> 4;
        const int rt = wave >> 1;            // 0..7 (16 rows each)
        const int c0 = (wave & 1) * 2;       // c tiles {c0, c0+1}
        f32x4 acc[2] = {(f32x4){0.f, 0.f, 0.f, 0.f}, (f32x4){0.f, 0.f, 0.f, 0.f}};
#pragma unroll
        for (int ks = 0; ks < 4; ++ks) {
            bf16_8 a = *(const bf16_8*)(Htile + (rt * 16 + r) * HS + ks * 32 + q * 8);
#pragma unroll
            for (int cc = 0; cc < 2; ++cc) {
                bf16_8 bb = *(const bf16_8*)&WB2[(((ks * 4 + (c0 + cc)) * 16 + r) * 4 + q) * 8];
                acc[cc] = __builtin_amdgcn_mfma_f32_16x16x32_bf16(a, bb, acc[cc], 0, 0, 0);
            }
        }
#pragma unroll
        for (int cc = 0; cc < 2; ++cc) {
#pragma unroll
            for (int i = 0; i < 4; ++i) {
                int tl = rt * 16 + q * 4 + i;
                int gnode = (b << BINSHIFT) + tl;
                if (gnode < NN)
                    Hw[(size_t)gnode * F_O + (c0 + cc) * 16 + r] =
                        __float2bfloat16(dv[tl] * acc[cc][i]);
            }
        }
    }
}

// ---------------------------------------------------------------------------
// Layer-2 aggregation: one wave per node, bin-local CSR (rp u16 + srcs_g),
// 8 lanes x 16B per row, 2 row-gathers in flight. Hw prescaled by dinv[src].
// out = dinv[v]*(sum_e Hw[s] + Hw[v]) + b2   (f32)
// ---------------------------------------------------------------------------
__global__ __launch_bounds__(256) void k_agg2(const __hip_bfloat16* __restrict__ Hw,
                                              const int* __restrict__ srcs_g,
                                              const unsigned short* __restrict__ rp_g,
                                              const float* __restrict__ b2,
                                              float* __restrict__ out) {
    const int wv   = (blockIdx.x * 256 + threadIdx.x) >> 6;
    const int lane = threadIdx.x & 63;
    if (wv >= NN) return;
    const int bin = wv >> BINSHIFT, tl = wv & 127;
    const int sub = lane >> 3;      // 0..7
    const int fl  = lane & 7;       // feature slice: 8*fl .. 8*fl+7
    const unsigned i0 = rp_g[bin * RPSTRIDE + tl];
    const unsigned i1 = rp_g[bin * RPSTRIDE + tl + 1];
    const int* srcs = srcs_g + (size_t)bin * CAP;

    float acc0[8], acc1[8];
    bf16_8 self = *(const bf16_8*)(Hw + (size_t)wv * F_O + fl * 8);
#pragma unroll
    for (int j = 0; j < 8; ++j) {
        acc0[j] = (sub == 0) ? (float)self[j] : 0.f;
        acc1[j] = 0.f;
    }

    unsigned i = i0 + sub;
    for (; i + 8 < i1; i += 16) {
        int s0 = srcs[i], s1 = srcs[i + 8];
        bf16_8 r0 = *(const bf16_8*)(Hw + (size_t)s0 * F_O + fl * 8);
        bf16_8 r1 = *(const bf16_8*)(Hw + (size_t)s1 * F_O + fl * 8);
#pragma unroll
        for (int j = 0; j < 8; ++j) {
            acc0[j] += (float)r0[j];
            acc1[j] += (float)r1[j];
        }
    }
    if (i < i1) {
        int s = srcs[i];
        bf16_8 r = *(const bf16_8*)(Hw + (size_t)s * F_O + fl * 8);
#pragma unroll
        for (int j = 0; j < 8; ++j) acc0[j] += (float)r[j];
    }
#pragma unroll
    for (int j = 0; j < 8; ++j) {
        float a = acc0[j] + acc1[j];
        a += __shfl_xor(a, 8, 64);
        a += __shfl_xor(a, 16, 64);
        a += __shfl_xor(a, 32, 64);
        acc0[j] = a;
    }
    if (sub == 0) {
        float dn = rsqrtf((float)(i1 - i0 + 1u));
        float4 o0 = make_float4(dn * acc0[0] + b2[fl * 8 + 0], dn * acc0[1] + b2[fl * 8 + 1],
                                dn * acc0[2] + b2[fl * 8 + 2], dn * acc0[3] + b2[fl * 8 + 3]);
        float4 o1 = make_float4(dn * acc0[4] + b2[fl * 8 + 4], dn * acc0[5] + b2[fl * 8 + 5],
                                dn * acc0[6] + b2[fl * 8 + 6], dn * acc0[7] + b2[fl * 8 + 7]);
        float4* op = (float4*)(out + (size_t)wv * F_O + fl * 8);
        op[0] = o0;
        op[1] = o1;
    }
}

// ---------------------------------------------------------------------------
extern "C" void kernel_launch(void* const* d_in, const int* in_sizes, int n_in,
                              void* d_out, int out_size, void* d_ws, size_t ws_size,
                              hipStream_t stream) {
    const float* x  = (const float*)d_in[0];
    const int*   ei = (const int*)d_in[1];
    const float* W1 = (const float*)d_in[2];
    const float* b1 = (const float*)d_in[3];
    const float* W2 = (const float*)d_in[4];
    const float* b2 = (const float*)d_in[5];
    float* out = (float*)d_out;

    char* w = (char*)d_ws;
    size_t off = 0;
    auto alloc = [&](size_t bytes) {
        void* p = w + off;
        off += (bytes + 255) & ~(size_t)255;
        return p;
    };
    unsigned* cnt     = (unsigned*)alloc((size_t)NN * 4);           // 200192 padded
    unsigned* bincnt  = (unsigned*)alloc((size_t)NBINS * 4);        // adjacent to cnt
    int*      binbuf  = (int*)alloc((size_t)NBINS * CAP * 4);
    int*      srcs    = (int*)alloc((size_t)NBINS * CAP * 4);
    unsigned short* rp = (unsigned short*)alloc((size_t)NBINS * RPSTRIDE * 2);
    __hip_bfloat16* Xw = (__hip_bfloat16*)alloc((size_t)NN * F_H * 2);
    __hip_bfloat16* Hw = (__hip_bfloat16*)alloc((size_t)NN * F_O * 2);

    // one memset covers cnt + bincnt (contiguous, 256B-padded allocs)
    size_t zlen = (((size_t)NN * 4 + 255) & ~(size_t)255) + (size_t)NBINS * 4;
    hipMemsetAsync(cnt, 0, zlen, stream);

    k_fuseA<<<NB_BIN + NB_G1, 256, 0, stream>>>(x, W1, Xw, ei, binbuf, bincnt, cnt);
    k_phaseC<<<NBINS, 1024, 0, stream>>>(binbuf, bincnt, cnt, Xw, W2, b1, Hw, srcs, rp);
    k_agg2<<<(NN + 3) / 4, 256, 0, stream>>>(Hw, srcs, rp, b2, out);
}

// Round 7
// 186.743 us; speedup vs baseline: 1.0676x; 1.0676x over previous
//
#include <hip/hip_runtime.h>
#include <hip/hip_bf16.h>

#define NN   50000
#define NE   800000
#define F_IN 128
#define F_H  128
#define F_O  64

#define BINSHIFT 7                       // 128 nodes per bin
#define NBINS    ((NN + 127) >> 7)       // 391
#define CAP      2816                    // mean 2048, sd ~45 -> +17 sigma
#define EPB      8192                    // edges per binning block (two-pass)

static constexpr int NB_G1  = (NN + 63) / 64;          // 782 GEMM1 blocks
static constexpr int NB_BIN = (NE + EPB - 1) / EPB;    // 98 binning blocks
static constexpr int NB_NODE = (NN + 255) / 256;

typedef __bf16 bf16_8 __attribute__((ext_vector_type(8)));
typedef float  f32x4  __attribute__((ext_vector_type(4)));

// ---------------------------------------------------------------------------
// MFMA GEMM body:  Y_bf16[r][c] = (SCALE ? dinv[r] : 1) * sum_k A[r][k]*W[k][c]
// Block = 64 rows (4 waves x 16 rows). W staged into LDS pre-swizzled to
// B-fragment layout [ks][c][q][r][j] — r-stride is 16B so one wave's b128
// reads cover all 8 bank-groups (the old [ks][c][r][q] put r at 64B stride:
// 2 of 8 groups -> 4x LDS serialization, 6.6M SQ_LDS_BANK_CONFLICT in r6).
// mfma_f32_16x16x32_bf16: A[m=lane&15][k=(lane>>4)*8+j],
//                         B[k][n=lane&15], D[row=(lane>>4)*4+reg][col=lane&15].
// ---------------------------------------------------------------------------
template <typename AT, int K, int NOUT, bool SCALE>
__device__ __forceinline__ void gemm_body(const AT* __restrict__ X,
                                          const float* __restrict__ W,
                                          const float* __restrict__ dinv,
                                          __hip_bfloat16* __restrict__ Y,
                                          __hip_bfloat16* WB, int blk) {
    constexpr int NKS = K / 32;
    constexpr int NC  = NOUT / 16;
    const int t = threadIdx.x;
    for (int f = t; f < K * NOUT; f += 256) {
        int k = f / NOUT, n = f % NOUT;
        int ks = k >> 5, kr = k & 31, qq = kr >> 3, jj = kr & 7;
        int c = n >> 4, nn = n & 15;
        WB[(((ks * NC + c) * 4 + qq) * 16 + nn) * 8 + jj] = __float2bfloat16(W[f]);
    }
    __syncthreads();

    const int wave = t >> 6, lane = t & 63;
    const int r = lane & 15, q = lane >> 4;
    const int m0 = blk * 64 + wave * 16;
    int arow = m0 + r;
    if (arow >= NN) arow = NN - 1;  // clamp: garbage rows computed, never stored

    f32x4 acc[NC];
#pragma unroll
    for (int c = 0; c < NC; ++c) acc[c] = (f32x4){0.f, 0.f, 0.f, 0.f};

#pragma unroll
    for (int ks = 0; ks < NKS; ++ks) {
        bf16_8 a;
        if constexpr (sizeof(AT) == 4) {
            const float* xp = (const float*)X + (size_t)arow * K + ks * 32 + q * 8;
            float4 x0 = ((const float4*)xp)[0];
            float4 x1 = ((const float4*)xp)[1];
            a[0] = (__bf16)x0.x; a[1] = (__bf16)x0.y; a[2] = (__bf16)x0.z; a[3] = (__bf16)x0.w;
            a[4] = (__bf16)x1.x; a[5] = (__bf16)x1.y; a[6] = (__bf16)x1.z; a[7] = (__bf16)x1.w;
        } else {
            a = *(const bf16_8*)((const __hip_bfloat16*)X + (size_t)arow * K + ks * 32 + q * 8);
        }
#pragma unroll
        for (int c = 0; c < NC; ++c) {
            bf16_8 b = *(const bf16_8*)&WB[(((ks * NC + c) * 4 + q) * 16 + r) * 8];
            acc[c] = __builtin_amdgcn_mfma_f32_16x16x32_bf16(a, b, acc[c], 0, 0, 0);
        }
    }

#pragma unroll
    for (int c = 0; c < NC; ++c) {
#pragma unroll
        for (int i = 0; i < 4; ++i) {
            int gr = m0 + q * 4 + i;
            if (gr < NN) {
                float v = acc[c][i];
                if constexpr (SCALE) v *= dinv[gr];
                Y[(size_t)gr * NOUT + c * 16 + r] = __float2bfloat16(v);
            }
        }
    }
}

// ---------------------------------------------------------------------------
// Fused: blocks [0, NB_BIN): bin edges by dst>>7 into packed binbuf, two-pass
//        (hist pass -> chunk reservation -> scatter pass). EPB=8192 makes
//        per-(block,bin) chunks ~84B >= a cache line, killing the r2/r6
//        partial-line write amplification on binbuf.
//        blocks [NB_BIN, ...): GEMM1 (x@W1 -> Xw, UNscaled).
// Packed entry: (src << 7) | (dst & 127).  bincnt[b] ends as bin total.
// ---------------------------------------------------------------------------
__global__ __launch_bounds__(256) void k_fuseA(const float* __restrict__ X,
                                               const float* __restrict__ W1,
                                               __hip_bfloat16* __restrict__ Xw,
                                               const int* __restrict__ ei32,
                                               int* __restrict__ binbuf,
                                               unsigned* __restrict__ bincnt) {
    __shared__ __align__(16) char smem[32768];  // GEMM WB (32KB) / binning hists
    const int t = threadIdx.x;

    if (blockIdx.x >= NB_BIN) {
        gemm_body<float, F_IN, F_H, false>(X, W1, nullptr, Xw,
                                           (__hip_bfloat16*)smem,
                                           blockIdx.x - NB_BIN);
        return;
    }

    // ---- binning role (two-pass) ----
    unsigned* hist = (unsigned*)smem;        // [NBINS]
    unsigned* base = hist + NBINS;           // [NBINS]
    unsigned* rank = base + NBINS;           // [NBINS]
    for (int i = t; i < NBINS; i += 256) { hist[i] = 0u; rank[i] = 0u; }
    __syncthreads();

    const bool is64 = ((ei32[1] | ei32[3] | ei32[5] | ei32[7]) == 0);
    const long long* p64 = (const long long*)ei32;
    const int e0 = blockIdx.x * EPB;
    const int e1 = (e0 + EPB < NE) ? e0 + EPB : NE;

    // pass 1: histogram of dst bins
    for (int e = e0 + t; e < e1; e += 256) {
        int d = is64 ? (int)p64[NE + e] : ei32[NE + e];
        atomicAdd(&hist[d >> BINSHIFT], 1u);
    }
    __syncthreads();
    for (int b = t; b < NBINS; b += 256)
        base[b] = atomicAdd(&bincnt[b], hist[b]);  // reserve contiguous chunk
    __syncthreads();
    // pass 2: scatter packed entries into reserved chunks
    for (int e = e0 + t; e < e1; e += 256) {
        int s, d;
        if (is64) { s = (int)p64[e]; d = (int)p64[NE + e]; }
        else      { s = ei32[e];     d = ei32[NE + e]; }
        int b = d >> BINSHIFT;
        unsigned rk = atomicAdd(&rank[b], 1u);
        binbuf[(size_t)b * CAP + base[b] + rk] = (s << BINSHIFT) | (d & 127);
    }
}

// ---------------------------------------------------------------------------
// Phase B (one block per bin): global base via masked sum of bincnt (inlined
// scan — no separate dispatch), local 128-node histogram, LDS scan ->
// row_ptr + dinv + LDS cursors, then scatter src ids into CSR.
// All atomics LDS; srcs writes confined to this bin's ~8KB region.
// ---------------------------------------------------------------------------
__global__ __launch_bounds__(256) void k_phaseB(const int* __restrict__ binbuf,
                                                const unsigned* __restrict__ bincnt,
                                                unsigned* __restrict__ row_ptr,
                                                float* __restrict__ dinv,
                                                int* __restrict__ srcs) {
    __shared__ unsigned h[128];
    __shared__ unsigned cur[128];
    __shared__ unsigned red[256];
    const int b = blockIdx.x, t = threadIdx.x;

    // base = sum_{i<b} bincnt[i]
    unsigned part = 0;
    for (int i = t; i < NBINS; i += 256)
        if (i < b) part += bincnt[i];
    red[t] = part;
    if (t < 128) h[t] = 0u;
    __syncthreads();
    for (int off = 128; off > 0; off >>= 1) {
        if (t < off) red[t] += red[t + off];
        __syncthreads();
    }
    const unsigned gbase = red[0];

    const unsigned n = bincnt[b];
    const int* buf = binbuf + (size_t)b * CAP;
    for (unsigned i = t; i < n; i += 256)
        atomicAdd(&h[buf[i] & 127], 1u);
    __syncthreads();
    if (t < 128) cur[t] = h[t];
    __syncthreads();
    for (int off = 1; off < 128; off <<= 1) {
        unsigned u = (t < 128 && t >= off) ? cur[t - off] : 0u;
        __syncthreads();
        if (t < 128) cur[t] += u;
        __syncthreads();
    }
    if (t < 128) {
        unsigned ex = gbase + cur[t] - h[t];  // global exclusive prefix
        int node = (b << BINSHIFT) + t;
        if (node < NN) {
            row_ptr[node] = ex;
            dinv[node]    = rsqrtf((float)(h[t] + 1u));  // +1 self-loop
        }
        cur[t] = ex;  // cursor
    }
    if (b == NBINS - 1 && t == 0) row_ptr[NN] = NE;
    __syncthreads();
    for (unsigned i = t; i < n; i += 256) {
        int p = buf[i];
        unsigned pos = atomicAdd(&cur[p & 127], 1u);
        srcs[pos] = p >> BINSHIFT;
    }
}

// ---------------------------------------------------------------------------
// Layer-1 aggregation: one wave per node, 16 lanes x 16B per gathered row,
// 2 independent row-gathers in flight per lane (8 edges per wave-iteration).
// H = relu(dinv[v]*(sum_e dinv[s]*Xw[s] + dinv[v]*Xw[v]) + b1)
// ---------------------------------------------------------------------------
__global__ __launch_bounds__(256) void k_agg1(const __hip_bfloat16* __restrict__ Xw,
                                              const int* __restrict__ srcs,
                                              const unsigned* __restrict__ row_ptr,
                                              const float* __restrict__ dinv,
                                              const float* __restrict__ b1,
                                              __hip_bfloat16* __restrict__ H) {
    const int wv   = (blockIdx.x * 256 + threadIdx.x) >> 6;
    const int lane = threadIdx.x & 63;
    if (wv >= NN) return;
    const int sub = lane >> 4;      // 0..3
    const int fl  = lane & 15;      // feature slice: 8*fl .. 8*fl+7
    const float dn = dinv[wv];

    float acc0[8], acc1[8];
    bf16_8 self = *(const bf16_8*)(Xw + (size_t)wv * F_H + fl * 8);
    const float sw = (sub == 0) ? dn : 0.f;
#pragma unroll
    for (int j = 0; j < 8; ++j) { acc0[j] = sw * (float)self[j]; acc1[j] = 0.f; }

    const unsigned ie = row_ptr[wv + 1];
    unsigned i = row_ptr[wv] + sub;
    for (; i + 4 < ie; i += 8) {   // two groups of 4 edges in flight
        int s0 = srcs[i], s1 = srcs[i + 4];
        float d0 = dinv[s0], d1 = dinv[s1];
        bf16_8 r0 = *(const bf16_8*)(Xw + (size_t)s0 * F_H + fl * 8);
        bf16_8 r1 = *(const bf16_8*)(Xw + (size_t)s1 * F_H + fl * 8);
#pragma unroll
        for (int j = 0; j < 8; ++j) {
            acc0[j] += d0 * (float)r0[j];
            acc1[j] += d1 * (float)r1[j];
        }
    }
    if (i < ie) {
        int s = srcs[i];
        float d = dinv[s];
        bf16_8 r = *(const bf16_8*)(Xw + (size_t)s * F_H + fl * 8);
#pragma unroll
        for (int j = 0; j < 8; ++j) acc0[j] += d * (float)r[j];
    }
#pragma unroll
    for (int j = 0; j < 8; ++j) {
        float a = acc0[j] + acc1[j];
        a += __shfl_xor(a, 16, 64);
        a += __shfl_xor(a, 32, 64);
        acc0[j] = a;
    }
    if (sub == 0) {
        bf16_8 o;
#pragma unroll
        for (int j = 0; j < 8; ++j) {
            float v = fmaxf(dn * acc0[j] + b1[fl * 8 + j], 0.f);
            o[j] = (__bf16)v;
        }
        *(bf16_8*)(H + (size_t)wv * F_H + fl * 8) = o;
    }
}

// Layer 2 GEMM (Hw = dinv * (H1 @ W2)), standalone.
__global__ __launch_bounds__(256) void k_gemm2(const __hip_bfloat16* __restrict__ H1,
                                               const float* __restrict__ W2,
                                               const float* __restrict__ dinv,
                                               __hip_bfloat16* __restrict__ Hw) {
    __shared__ __align__(16) __hip_bfloat16 WB[(F_H / 32) * (F_O / 16) * 512];
    gemm_body<__hip_bfloat16, F_H, F_O, true>(H1, W2, dinv, Hw, WB, blockIdx.x);
}

// ---------------------------------------------------------------------------
// Layer-2 aggregation: one wave per node, 8 lanes x 16B per row, 2 row-gathers
// in flight per lane (16 edges per wave-iteration). Hw pre-scaled by dinv[src].
// out = dinv[v]*(sum_e Hw[s] + Hw[v]) + b2   (f32 output)
// ---------------------------------------------------------------------------
__global__ __launch_bounds__(256) void k_agg2(const __hip_bfloat16* __restrict__ Hw,
                                              const int* __restrict__ srcs,
                                              const unsigned* __restrict__ row_ptr,
                                              const float* __restrict__ dinv,
                                              const float* __restrict__ b2,
                                              float* __restrict__ out) {
    const int wv   = (blockIdx.x * 256 + threadIdx.x) >> 6;
    const int lane = threadIdx.x & 63;
    if (wv >= NN) return;
    const int sub = lane >> 3;      // 0..7
    const int fl  = lane & 7;       // feature slice: 8*fl .. 8*fl+7

    float acc0[8], acc1[8];
    bf16_8 self = *(const bf16_8*)(Hw + (size_t)wv * F_O + fl * 8);
#pragma unroll
    for (int j = 0; j < 8; ++j) {
        acc0[j] = (sub == 0) ? (float)self[j] : 0.f;
        acc1[j] = 0.f;
    }

    const unsigned ie = row_ptr[wv + 1];
    unsigned i = row_ptr[wv] + sub;
    for (; i + 8 < ie; i += 16) {  // two groups of 8 edges in flight
        int s0 = srcs[i], s1 = srcs[i + 8];
        bf16_8 r0 = *(const bf16_8*)(Hw + (size_t)s0 * F_O + fl * 8);
        bf16_8 r1 = *(const bf16_8*)(Hw + (size_t)s1 * F_O + fl * 8);
#pragma unroll
        for (int j = 0; j < 8; ++j) {
            acc0[j] += (float)r0[j];
            acc1[j] += (float)r1[j];
        }
    }
    if (i < ie) {
        int s = srcs[i];
        bf16_8 r = *(const bf16_8*)(Hw + (size_t)s * F_O + fl * 8);
#pragma unroll
        for (int j = 0; j < 8; ++j) acc0[j] += (float)r[j];
    }
#pragma unroll
    for (int j = 0; j < 8; ++j) {
        float a = acc0[j] + acc1[j];
        a += __shfl_xor(a, 8, 64);
        a += __shfl_xor(a, 16, 64);
        a += __shfl_xor(a, 32, 64);
        acc0[j] = a;
    }
    if (sub == 0) {
        float dn = dinv[wv];
        float4 o0 = make_float4(dn * acc0[0] + b2[fl * 8 + 0], dn * acc0[1] + b2[fl * 8 + 1],
                                dn * acc0[2] + b2[fl * 8 + 2], dn * acc0[3] + b2[fl * 8 + 3]);
        float4 o1 = make_float4(dn * acc0[4] + b2[fl * 8 + 4], dn * acc0[5] + b2[fl * 8 + 5],
                                dn * acc0[6] + b2[fl * 8 + 6], dn * acc0[7] + b2[fl * 8 + 7]);
        float4* op = (float4*)(out + (size_t)wv * F_O + fl * 8);
        op[0] = o0;
        op[1] = o1;
    }
}

// ---------------------------------------------------------------------------
extern "C" void kernel_launch(void* const* d_in, const int* in_sizes, int n_in,
                              void* d_out, int out_size, void* d_ws, size_t ws_size,
                              hipStream_t stream) {
    const float* x  = (const float*)d_in[0];
    const int*   ei = (const int*)d_in[1];
    const float* W1 = (const float*)d_in[2];
    const float* b1 = (const float*)d_in[3];
    const float* W2 = (const float*)d_in[4];
    const float* b2 = (const float*)d_in[5];
    float* out = (float*)d_out;

    char* w = (char*)d_ws;
    size_t off = 0;
    auto alloc = [&](size_t bytes) {
        void* p = w + off;
        off += (bytes + 255) & ~(size_t)255;
        return p;
    };
    unsigned* row_ptr = (unsigned*)alloc((size_t)(NN + 1) * 4);
    float*    dinv    = (float*)alloc((size_t)NN * 4);
    unsigned* bincnt  = (unsigned*)alloc((size_t)NBINS * 4);
    int*      srcs    = (int*)alloc((size_t)NE * 4);
    int*      binbuf  = (int*)alloc((size_t)NBINS * CAP * 4);
    __hip_bfloat16* Xw = (__hip_bfloat16*)alloc((size_t)NN * F_H * 2);  // reused as Hw
    __hip_bfloat16* H1 = (__hip_bfloat16*)alloc((size_t)NN * F_H * 2);
    __hip_bfloat16* Hw = Xw;  // alias: Xw dead after k_agg1

    hipMemsetAsync(bincnt, 0, (size_t)NBINS * 4, stream);
    k_fuseA<<<NB_BIN + NB_G1, 256, 0, stream>>>(x, W1, Xw, ei, binbuf, bincnt);
    k_phaseB<<<NBINS, 256, 0, stream>>>(binbuf, bincnt, row_ptr, dinv, srcs);

    k_agg1<<<(NN + 3) / 4, 256, 0, stream>>>(Xw, srcs, row_ptr, dinv, b1, H1);
    k_gemm2<<<(NN + 63) / 64, 256, 0, stream>>>(H1, W2, dinv, Hw);
    k_agg2<<<(NN + 3) / 4, 256, 0, stream>>>(Hw, srcs, row_ptr, dinv, b2, out);
}